// Round 5
// baseline (58942.920 us; speedup 1.0000x reference)
//
#include <hip/hip_runtime.h>
#include <hip/hip_bf16.h>
#include <math.h>

using bf16 = __hip_bfloat16;
typedef __bf16 bf16x8 __attribute__((ext_vector_type(8)));
typedef float f32x4 __attribute__((ext_vector_type(4)));

// Problem dims
static constexpr int NB = 512;    // batch
static constexpr int NH = 1024;   // hidden
static constexpr int NOH = 4096;  // MLP inner
static constexpr int NC = 512;    // classes
static constexpr int NT = 40;     // timestamps
static constexpr int SPLITK = 4;  // GEMM2 split-K slices
static constexpr int NWG = 512;   // persistent workgroups (2 per CU)
static constexpr int NGRP = 8;    // barrier tree fan-in groups
static constexpr int GRPSZ = NWG / NGRP;  // 64 blocks per group

// Barrier state layout (unsigned words), zeroed by init_state every launch:
//   [0..NGRP*32)   group counters, 128B apart
//   [NGRP*32]      top counter
//   [NGRP*32+1]    generation
//   [NGRP*32+2]    abort flag
static constexpr int BAR_WORDS = NGRP * 32 + 3;

#define AL(p, mo) __hip_atomic_load((p), (mo), __HIP_MEMORY_SCOPE_AGENT)
#define AS(p, v, mo) __hip_atomic_store((p), (v), (mo), __HIP_MEMORY_SCOPE_AGENT)
#define AFA(p, v, mo) __hip_atomic_fetch_add((p), (v), (mo), __HIP_MEMORY_SCOPE_AGENT)

// ---------------------------------------------------------------------------
// Transpose-cast fp32 (K x N) -> bf16 (N x K)
// ---------------------------------------------------------------------------
__global__ void transpose_cast(const float* __restrict__ W, bf16* __restrict__ WT,
                               int K, int N) {
  __shared__ float tile[32][33];
  const int n0 = blockIdx.x * 32;
  const int k0 = blockIdx.y * 32;
  const int tx = threadIdx.x;  // 0..31
  const int ty = threadIdx.y;  // 0..7
#pragma unroll
  for (int i = 0; i < 4; ++i) {
    int r = ty + i * 8;
    tile[r][tx] = W[(size_t)(k0 + r) * N + n0 + tx];
  }
  __syncthreads();
#pragma unroll
  for (int i = 0; i < 4; ++i) {
    int r = ty + i * 8;
    WT[(size_t)(n0 + r) * K + k0 + tx] = __float2bfloat16(tile[tx][r]);
  }
}

// ---------------------------------------------------------------------------
// Init: y = z, yb = bf16(z), pred[0] = bf16(z); block 0 zeroes barrier state.
// ---------------------------------------------------------------------------
__global__ void init_state(const float* __restrict__ z, float* __restrict__ y,
                           bf16* __restrict__ yb, bf16* __restrict__ pred0,
                           unsigned* __restrict__ bar) {
  const int i = blockIdx.x * 256 + threadIdx.x;
  if (blockIdx.x == 0) {
    for (int j = threadIdx.x; j < BAR_WORDS; j += 256) bar[j] = 0u;
  }
  float v = z[i];
  y[i] = v;
  bf16 b = __float2bfloat16(v);
  yb[i] = b;
  pred0[i] = b;
}

// ---------------------------------------------------------------------------
// Two-level grid barrier (sense via generation counter).  Returns false on
// abort (bounded spin exceeded somewhere -> fail gracefully, no hang).
// ---------------------------------------------------------------------------
__device__ __forceinline__ bool grid_bar(unsigned* __restrict__ bar) {
  __threadfence();   // release this thread's prior writes (agent scope)
  __syncthreads();   // all waves of block drained (vmcnt0 at barrier)
  __shared__ int ok_s;
  if (threadIdx.x == 0) {
    unsigned* grp = bar + (blockIdx.x & (NGRP - 1)) * 32;
    unsigned* top = bar + NGRP * 32;
    unsigned* gen = top + 1;
    unsigned* abt = top + 2;
    int good = 1;
    const unsigned g = AL(gen, __ATOMIC_RELAXED);
    const unsigned a = AFA(grp, 1u, __ATOMIC_ACQ_REL);
    bool bumped = false;
    if (a == GRPSZ - 1) {
      AS(grp, 0u, __ATOMIC_RELAXED);
      const unsigned b = AFA(top, 1u, __ATOMIC_ACQ_REL);
      if (b == NGRP - 1) {
        AS(top, 0u, __ATOMIC_RELAXED);
        AFA(gen, 1u, __ATOMIC_RELEASE);
        bumped = true;
      }
    }
    if (!bumped) {
      long spins = 0;
      while (AL(gen, __ATOMIC_ACQUIRE) == g) {
        __builtin_amdgcn_s_sleep(2);
        if ((++spins & 255) == 0 && AL(abt, __ATOMIC_RELAXED) != 0u) { good = 0; break; }
        if (spins > (1L << 23)) {  // ~1s: co-residency failed; bail out
          AS(abt, 1u, __ATOMIC_RELAXED);
          good = 0;
          break;
        }
      }
    }
    ok_s = good;
  }
  __syncthreads();
  __threadfence();   // acquire: invalidate stale cached data before next phase
  return ok_s != 0;
}

// ---------------------------------------------------------------------------
// Persistent kernel: entire RK4 time loop.  512 WGs x 256 threads (2/CU).
// Per stage: A: h = tanh(yb@W1+b1) (512 64x64 tiles) | bar |
//            B: part[kz] = h@W2 chunk (128 tiles x SPLITK) | bar |
//            C: combine + RK4 algebra -> yb (y, pred at s=4) | bar |
// GEMM core: 64x64 tile, BK=64, 4 waves 2x2, dbuf LDS prefetch pipeline.
// ---------------------------------------------------------------------------
__global__ __launch_bounds__(256, 2) void ode_persistent(
    const bf16* __restrict__ W1bT, const bf16* __restrict__ W2bT,
    const float* __restrict__ b1, const float* __restrict__ b2,
    const float* __restrict__ ts, float* __restrict__ y, bf16* __restrict__ yb,
    float* __restrict__ k1, float* __restrict__ k2, float* __restrict__ k3,
    bf16* __restrict__ h, float* __restrict__ part, bf16* __restrict__ pred,
    unsigned* __restrict__ bar) {
  __shared__ __align__(16) bf16 As[2][64 * 64];
  __shared__ __align__(16) bf16 Bs[2][64 * 64];

  const int tid = threadIdx.x;
  const int lane = tid & 63;
  const int wave = tid >> 6;
  const int wr = wave >> 1;
  const int wc = wave & 1;
  const int l15 = lane & 15;
  const int kg = lane >> 4;
  const int sr = wave * 8 + (lane >> 3);  // staging row within 32-row round
  const int cb = (lane & 7) * 8;          // staging col element offset
  const int wg = blockIdx.x;

  // phase A task: 8 x 64 tiles of [512 x 4096]
  const int a_row0 = (wg >> 6) * 64;
  const int a_col0 = (wg & 63) * 64;
  // phase B task: SPLITK x (8 x 16) tiles of [512 x 1024]
  const int b_kz = wg >> 7;
  const int b_row0 = ((wg >> 4) & 7) * 64;
  const int b_col0 = (wg & 15) * 64;
  const int b_kbeg = b_kz * (NOH / SPLITK);
  // phase C element (one f32x4 per thread; NWG*256*4 == NB*NH exactly)
  const int ci = wg * 256 + tid;

  auto mm = [&](const bf16* __restrict__ A, const bf16* __restrict__ BT, int K,
                int kbeg, int kend, int row0, int col0, f32x4 (&acc)[2][2]) {
#pragma unroll
    for (int mi = 0; mi < 2; ++mi)
#pragma unroll
      for (int ni = 0; ni < 2; ++ni) acc[mi][ni] = f32x4{0.f, 0.f, 0.f, 0.f};

    auto stage = [&](int buf, int kt) {
#pragma unroll
      for (int i = 0; i < 2; ++i) {
        const bf16* ga = A + (size_t)(row0 + i * 32 + sr) * K + kt + cb;
        __builtin_amdgcn_global_load_lds(
            (const __attribute__((address_space(1))) void*)ga,
            (__attribute__((address_space(3))) void*)&As[buf][(i * 32 + wave * 8) * 64],
            16, 0, 0);
        const bf16* gb = BT + (size_t)(col0 + i * 32 + sr) * K + kt + cb;
        __builtin_amdgcn_global_load_lds(
            (const __attribute__((address_space(1))) void*)gb,
            (__attribute__((address_space(3))) void*)&Bs[buf][(i * 32 + wave * 8) * 64],
            16, 0, 0);
      }
    };

    stage(0, kbeg);
    __syncthreads();
    int cur = 0;
    for (int kt = kbeg; kt < kend; kt += 64) {
      if (kt + 64 < kend) stage(cur ^ 1, kt + 64);  // prefetch next tile
#pragma unroll
      for (int ks = 0; ks < 64; ks += 32) {
        bf16x8 af[2], bfr[2];
        const int kb = ks + kg * 8;
#pragma unroll
        for (int mi = 0; mi < 2; ++mi)
          af[mi] = *reinterpret_cast<const bf16x8*>(
              &As[cur][(wr * 32 + mi * 16 + l15) * 64 + kb]);
#pragma unroll
        for (int ni = 0; ni < 2; ++ni)
          bfr[ni] = *reinterpret_cast<const bf16x8*>(
              &Bs[cur][(wc * 32 + ni * 16 + l15) * 64 + kb]);
#pragma unroll
        for (int mi = 0; mi < 2; ++mi)
#pragma unroll
          for (int ni = 0; ni < 2; ++ni)
            acc[mi][ni] = __builtin_amdgcn_mfma_f32_16x16x32_bf16(
                af[mi], bfr[ni], acc[mi][ni], 0, 0, 0);
      }
      __syncthreads();  // prefetched tile ready (vmcnt drain at barrier)
      cur ^= 1;
    }
  };

#pragma unroll 1
  for (int t = 0; t < NT - 1; ++t) {
    const float dt = ts[t + 1] - ts[t];
#pragma unroll 1
    for (int s = 1; s <= 4; ++s) {
      // ---- phase A: h = tanh(yb @ W1 + b1) ----
      {
        f32x4 acc[2][2];
        mm(yb, W1bT, NH, 0, NH, a_row0, a_col0, acc);
#pragma unroll
        for (int mi = 0; mi < 2; ++mi) {
          const int grow = a_row0 + wr * 32 + mi * 16 + kg * 4;
#pragma unroll
          for (int ni = 0; ni < 2; ++ni) {
            const int gcol = a_col0 + wc * 32 + ni * 16 + l15;
            const float bias = b1[gcol];
#pragma unroll
            for (int j = 0; j < 4; ++j)
              h[(size_t)(grow + j) * NOH + gcol] =
                  __float2bfloat16(tanhf(acc[mi][ni][j] + bias));
          }
        }
      }
      if (!grid_bar(bar)) return;

      // ---- phase B: part[kz] = (h @ W2) K-chunk ----
      {
        f32x4 acc[2][2];
        mm(h, W2bT, NOH, b_kbeg, b_kbeg + NOH / SPLITK, b_row0, b_col0, acc);
        float* pz = part + (size_t)b_kz * NB * NH;
#pragma unroll
        for (int mi = 0; mi < 2; ++mi) {
          const int grow = b_row0 + wr * 32 + mi * 16 + kg * 4;
#pragma unroll
          for (int ni = 0; ni < 2; ++ni) {
            const int gcol = b_col0 + wc * 32 + ni * 16 + l15;
#pragma unroll
            for (int j = 0; j < 4; ++j)
              pz[(size_t)(grow + j) * NH + gcol] = acc[mi][ni][j];
          }
        }
      }
      if (!grid_bar(bar)) return;

      // ---- phase C: combine split-K + RK4 stage algebra ----
      {
        f32x4 sum = {};
#pragma unroll
        for (int z2 = 0; z2 < SPLITK; ++z2)
          sum += *reinterpret_cast<const f32x4*>(part + (size_t)z2 * NB * NH +
                                                 (size_t)ci * 4);
        const int col = (ci * 4) & (NH - 1);
        const f32x4 bb = *reinterpret_cast<const f32x4*>(b2 + col);
        const f32x4 ksv = sum + bb;
        const f32x4 yv = *reinterpret_cast<const f32x4*>(y + (size_t)ci * 4);

        f32x4 ynext;
        if (s == 1) {
          *reinterpret_cast<f32x4*>(k1 + (size_t)ci * 4) = ksv;
          ynext = yv + ksv * (dt / 3.0f);
        } else if (s == 2) {
          const f32x4 k1v = *reinterpret_cast<const f32x4*>(k1 + (size_t)ci * 4);
          *reinterpret_cast<f32x4*>(k2 + (size_t)ci * 4) = ksv;
          ynext = yv + (ksv - k1v * (1.0f / 3.0f)) * dt;
        } else if (s == 3) {
          const f32x4 k1v = *reinterpret_cast<const f32x4*>(k1 + (size_t)ci * 4);
          const f32x4 k2v = *reinterpret_cast<const f32x4*>(k2 + (size_t)ci * 4);
          *reinterpret_cast<f32x4*>(k3 + (size_t)ci * 4) = ksv;
          ynext = yv + (k1v - k2v + ksv) * dt;
        } else {
          const f32x4 k1v = *reinterpret_cast<const f32x4*>(k1 + (size_t)ci * 4);
          const f32x4 k2v = *reinterpret_cast<const f32x4*>(k2 + (size_t)ci * 4);
          const f32x4 k3v = *reinterpret_cast<const f32x4*>(k3 + (size_t)ci * 4);
          ynext = yv + (k1v + (k2v + k3v) * 3.0f + ksv) * (dt * 0.125f);
          *reinterpret_cast<f32x4*>(y + (size_t)ci * 4) = ynext;
          union { bf16 hh[4]; unsigned long long u; } pk;
#pragma unroll
          for (int j = 0; j < 4; ++j) pk.hh[j] = __float2bfloat16(ynext[j]);
          *reinterpret_cast<unsigned long long*>(
              pred + (size_t)(t + 1) * NB * NH + (size_t)ci * 4) = pk.u;
        }
        union { bf16 hh[4]; unsigned long long u; } pk2;
#pragma unroll
        for (int j = 0; j < 4; ++j) pk2.hh[j] = __float2bfloat16(ynext[j]);
        *reinterpret_cast<unsigned long long*>(yb + (size_t)ci * 4) = pk2.u;
      }
      if (!grid_bar(bar)) return;
    }
  }
}

// ---------------------------------------------------------------------------
// Final projection GEMM: 128x128 tile, dbuf prefetch.  out = A @ BT^T + bias
// ---------------------------------------------------------------------------
__global__ __launch_bounds__(256) void proj_gemm(
    const bf16* __restrict__ A, const bf16* __restrict__ BT,
    int M, int N, int K, const float* __restrict__ bias,
    float* __restrict__ outF) {
  constexpr int TM = 128, TN = 128;

  __shared__ __align__(16) bf16 As[2][TM * 64];
  __shared__ __align__(16) bf16 Bs[2][TN * 64];

  const int tid = threadIdx.x;
  const int lane = tid & 63;
  const int wave = tid >> 6;
  const int wr = wave >> 1;
  const int wc = wave & 1;
  const int row0 = blockIdx.y * TM;
  const int col0 = blockIdx.x * TN;
  const int l15 = lane & 15;
  const int kg = lane >> 4;
  const int sr = wave * 8 + (lane >> 3);
  const int cb = (lane & 7) * 8;

  f32x4 acc[4][4] = {};

  auto stage = [&](int buf, int kt) {
#pragma unroll
    for (int i = 0; i < 4; ++i) {
      const bf16* ga = A + (size_t)(row0 + i * 32 + sr) * K + kt + cb;
      __builtin_amdgcn_global_load_lds(
          (const __attribute__((address_space(1))) void*)ga,
          (__attribute__((address_space(3))) void*)&As[buf][(i * 32 + wave * 8) * 64],
          16, 0, 0);
      const bf16* gb = BT + (size_t)(col0 + i * 32 + sr) * K + kt + cb;
      __builtin_amdgcn_global_load_lds(
          (const __attribute__((address_space(1))) void*)gb,
          (__attribute__((address_space(3))) void*)&Bs[buf][(i * 32 + wave * 8) * 64],
          16, 0, 0);
    }
  };

  stage(0, 0);
  __syncthreads();
  int cur = 0;

  for (int kt = 0; kt < K; kt += 64) {
    if (kt + 64 < K) stage(cur ^ 1, kt + 64);
#pragma unroll
    for (int ks = 0; ks < 64; ks += 32) {
      bf16x8 af[4], bfr[4];
      const int kb = ks + kg * 8;
#pragma unroll
      for (int mi = 0; mi < 4; ++mi)
        af[mi] = *reinterpret_cast<const bf16x8*>(
            &As[cur][(wr * 64 + mi * 16 + l15) * 64 + kb]);
#pragma unroll
      for (int ni = 0; ni < 4; ++ni)
        bfr[ni] = *reinterpret_cast<const bf16x8*>(
            &Bs[cur][(wc * 64 + ni * 16 + l15) * 64 + kb]);
#pragma unroll
      for (int mi = 0; mi < 4; ++mi)
#pragma unroll
        for (int ni = 0; ni < 4; ++ni)
          acc[mi][ni] = __builtin_amdgcn_mfma_f32_16x16x32_bf16(
              af[mi], bfr[ni], acc[mi][ni], 0, 0, 0);
    }
    __syncthreads();
    cur ^= 1;
  }

#pragma unroll
  for (int mi = 0; mi < 4; ++mi) {
    const int grow_base = row0 + wr * 64 + mi * 16 + kg * 4;
#pragma unroll
    for (int ni = 0; ni < 4; ++ni) {
      const int gcol = col0 + wc * 64 + ni * 16 + l15;
#pragma unroll
      for (int j = 0; j < 4; ++j)
        outF[(size_t)(grow_base + j) * N + gcol] = acc[mi][ni][j] + bias[gcol];
    }
  }
}

// ---------------------------------------------------------------------------
// In-place row softmax over C=512; one wave per row.
// ---------------------------------------------------------------------------
__global__ void softmax_rows(float* __restrict__ out) {
  const int row = blockIdx.x * 4 + (threadIdx.x >> 6);
  const int lane = threadIdx.x & 63;
  float* p = out + (size_t)row * NC + lane * 8;
  f32x4 a = *reinterpret_cast<const f32x4*>(p);
  f32x4 b = *reinterpret_cast<const f32x4*>(p + 4);

  float m = fmaxf(fmaxf(fmaxf(a[0], a[1]), fmaxf(a[2], a[3])),
                  fmaxf(fmaxf(b[0], b[1]), fmaxf(b[2], b[3])));
#pragma unroll
  for (int off = 32; off > 0; off >>= 1) m = fmaxf(m, __shfl_xor(m, off));

  f32x4 ea, eb;
  float sum = 0.0f;
#pragma unroll
  for (int j = 0; j < 4; ++j) { ea[j] = expf(a[j] - m); sum += ea[j]; }
#pragma unroll
  for (int j = 0; j < 4; ++j) { eb[j] = expf(b[j] - m); sum += eb[j]; }
#pragma unroll
  for (int off = 32; off > 0; off >>= 1) sum += __shfl_xor(sum, off);

  const float inv = 1.0f / sum;
  ea *= inv;
  eb *= inv;
  *reinterpret_cast<f32x4*>(p) = ea;
  *reinterpret_cast<f32x4*>(p + 4) = eb;
}

// ---------------------------------------------------------------------------
extern "C" void kernel_launch(void* const* d_in, const int* in_sizes, int n_in,
                              void* d_out, int out_size, void* d_ws, size_t ws_size,
                              hipStream_t stream) {
  const float* z = (const float*)d_in[0];
  const float* ts = (const float*)d_in[1];
  const float* W1 = (const float*)d_in[2];
  const float* b1 = (const float*)d_in[3];
  const float* W2 = (const float*)d_in[4];
  const float* b2 = (const float*)d_in[5];
  const float* Wf = (const float*)d_in[6];
  const float* bfv = (const float*)d_in[7];

  char* w = (char*)d_ws;
  bf16* W1bT = (bf16*)w;          w += (size_t)NOH * NH * 2;         // 8 MB
  bf16* W2bT = (bf16*)w;          w += (size_t)NH * NOH * 2;         // 8 MB
  bf16* WfT  = (bf16*)w;          w += (size_t)NC * NH * 2;          // 1 MB
  float* y   = (float*)w;         w += (size_t)NB * NH * 4;          // 2 MB
  bf16* yb   = (bf16*)w;          w += (size_t)NB * NH * 2;          // 1 MB
  float* k1  = (float*)w;         w += (size_t)NB * NH * 4;
  float* k2  = (float*)w;         w += (size_t)NB * NH * 4;
  float* k3  = (float*)w;         w += (size_t)NB * NH * 4;          // 6 MB
  bf16* h    = (bf16*)w;          w += (size_t)NB * NOH * 2;         // 4 MB
  float* part = (float*)w;        w += (size_t)SPLITK * NB * NH * 4; // 8 MB
  bf16* pred = (bf16*)w;          w += (size_t)NT * NB * NH * 2;     // 40 MB
  unsigned* bar = (unsigned*)w;   w += BAR_WORDS * 4;

  float* logits = (float*)d_out;  // [NT*NB, NC] fp32, softmaxed in place

  // Weight transpose-casts + state/barrier init (stateless: rerun every call)
  transpose_cast<<<dim3(NOH / 32, NH / 32), dim3(32, 8), 0, stream>>>(W1, W1bT, NH, NOH);
  transpose_cast<<<dim3(NH / 32, NOH / 32), dim3(32, 8), 0, stream>>>(W2, W2bT, NOH, NH);
  transpose_cast<<<dim3(NC / 32, NH / 32), dim3(32, 8), 0, stream>>>(Wf, WfT, NH, NC);
  init_state<<<(NB * NH) / 256, 256, 0, stream>>>(z, y, yb, pred, bar);

  // Entire RK4 loop in one persistent kernel (manual grid barrier; 512 blocks
  // = 2/CU guaranteed co-resident by __launch_bounds__(256,2) + 32KB LDS)
  ode_persistent<<<dim3(NWG), dim3(256), 0, stream>>>(
      W1bT, W2bT, b1, b2, ts, y, yb, k1, k2, k3, h, part, pred, bar);

  // logits = pred @ Wf + bf   [20480 x 512], then softmax
  proj_gemm<<<dim3(NC / 128, (NT * NB) / 128), 256, 0, stream>>>(
      pred, WfT, NT * NB, NC, NH, bfv, logits);
  softmax_rows<<<(NT * NB) / 4, 256, 0, stream>>>(logits);
}

// Round 6
// 34134.192 us; speedup vs baseline: 1.7268x; 1.7268x over previous
//
#include <hip/hip_runtime.h>
#include <hip/hip_bf16.h>
#include <math.h>

using bf16 = __hip_bfloat16;
typedef __bf16 bf16x8 __attribute__((ext_vector_type(8)));
typedef float f32x4 __attribute__((ext_vector_type(4)));

// Problem dims
static constexpr int NB = 512, NH = 1024, NOH = 4096, NC = 512, NT = 40;
// Pipeline decomposition
static constexpr int R = 32;                 // batch rows per rowblock
static constexpr int NRB = NB / R;           // 16 rowblocks
static constexpr int NSTR = 16;              // weight strips
static constexpr int SW = NOH / NSTR;        // 256 OH cols per strip
static constexpr int PHASES = (NT - 1) * 4;  // 156 RK4 stages
// sync buffer layout (unsigned words)
static constexpr int CNT_OFF = 0;                   // [PHASES*NRB] arrivals
static constexpr int CD_OFF = PHASES * NRB;         // [PHASES*NRB] C-half done
static constexpr int FLAG_OFF = 2 * PHASES * NRB;   // [NRB] yb generation
static constexpr int ABT_OFF = FLAG_OFF + NRB;      // abort flag
static constexpr int SYNC_WORDS = ABT_OFF + 1;

#define AL(p) __hip_atomic_load((p), __ATOMIC_RELAXED, __HIP_MEMORY_SCOPE_AGENT)
#define AS(p, v) __hip_atomic_store((p), (v), __ATOMIC_RELAXED, __HIP_MEMORY_SCOPE_AGENT)
#define AFA(p, v) __hip_atomic_fetch_add((p), (v), __ATOMIC_RELAXED, __HIP_MEMORY_SCOPE_AGENT)

__device__ __forceinline__ float lo32f(unsigned long long v) {
  return __uint_as_float((unsigned)v);
}
__device__ __forceinline__ float hi32f(unsigned long long v) {
  return __uint_as_float((unsigned)(v >> 32));
}
__device__ __forceinline__ unsigned long long packf2(float a, float b) {
  return ((unsigned long long)__float_as_uint(b) << 32) | __float_as_uint(a);
}
__device__ __forceinline__ unsigned packbf(float a, float b) {
  union { bf16 h[2]; unsigned u; } pk;
  pk.h[0] = __float2bfloat16(a);
  pk.h[1] = __float2bfloat16(b);
  return pk.u;
}

// ---------------------------------------------------------------------------
// Transpose-cast fp32 (K x N) -> bf16 (N x K).  SWZ: bake the T2 XOR-swizzle
// (16B units permuted within each 64-elem k-window by row&7) into the layout
// so a linear global_load_lds stage lands swizzled data in LDS.
// ---------------------------------------------------------------------------
template <bool SWZ>
__global__ void transpose_cast(const float* __restrict__ W, bf16* __restrict__ WT,
                               int K, int N) {
  __shared__ float tile[32][33];
  const int n0 = blockIdx.x * 32;
  const int k0 = blockIdx.y * 32;
  const int tx = threadIdx.x;  // 0..31
  const int ty = threadIdx.y;  // 0..7
#pragma unroll
  for (int i = 0; i < 4; ++i) {
    int r = ty + i * 8;
    tile[r][tx] = W[(size_t)(k0 + r) * N + n0 + tx];
  }
  __syncthreads();
#pragma unroll
  for (int i = 0; i < 4; ++i) {
    int r = ty + i * 8;
    const int n = n0 + r, k = k0 + tx;
    size_t idx;
    if constexpr (SWZ) {
      idx = (size_t)n * K + (k & ~63) + (((k & 63) ^ ((n & 7) << 3)));
    } else {
      idx = (size_t)n * K + k;
    }
    WT[idx] = __float2bfloat16(tile[tx][r]);
  }
}

// ---------------------------------------------------------------------------
// Init: y = z, yb = bf16(z), pred[0] = bf16(z); zero part accumulators and
// sync words.  Grid 2048x256 covers NB*NH.
// ---------------------------------------------------------------------------
__global__ void init_state(const float* __restrict__ z, float* __restrict__ y,
                           bf16* __restrict__ yb, bf16* __restrict__ pred0,
                           float* __restrict__ part, unsigned* __restrict__ sy) {
  const int i = blockIdx.x * 256 + threadIdx.x;  // < 524288
  float v = z[i];
  y[i] = v;
  bf16 b = __float2bfloat16(v);
  yb[i] = b;
  pred0[i] = b;
#pragma unroll
  for (int j = 0; j < 8; ++j) part[(size_t)j * (NB * NH) + i] = 0.f;
  if (i < SYNC_WORDS) sy[i] = 0u;
}

// ---------------------------------------------------------------------------
// Persistent pipelined RK4 kernel.  Grid 256 = 16 rowblocks x 16 strips.
// Per phase p (= RK4 stage), block (rb, strip):
//   spin flag[rb] >= p  (relaxed; yb gen p available)
//   stage yb rows (sc1 loads -> swizzled LDS)
//   GEMM-A: Hs = tanh(yb @ W1strip + b1)       (LDS only, 16 BK=64 tiles)
//   GEMM-B: atomicAdd(part[strip>>1][rb], Hs @ W2strip)   (16 tiles)
//   arrive cnt[p][rb]; last two arrivers each do half the RK4 combine:
//     ks = sum(part slices)+b2 (and re-zero), stage algebra -> yb (sc1),
//     y/k1..k3 (sc1), pred at s=4 (plain); then flag[rb] = p+1.
// No fences, no L2 maintenance anywhere: weights stay L2-resident.
// ---------------------------------------------------------------------------
__global__ __launch_bounds__(256, 1) void ode_pipeline(
    const bf16* __restrict__ W1bT, const bf16* __restrict__ W2bT,
    const float* __restrict__ b1, const float* __restrict__ b2,
    const float* __restrict__ ts, float* __restrict__ y, bf16* __restrict__ yb,
    float* __restrict__ k1, float* __restrict__ k2, float* __restrict__ k3,
    float* __restrict__ part, bf16* __restrict__ pred,
    unsigned* __restrict__ sy) {
  extern __shared__ __align__(16) char smem[];
  bf16* YB = (bf16*)smem;                        // 32 x 1024, swizzled (64KB)
  bf16* Hs = (bf16*)(smem + 65536);              // 32 x 256, swizzled  (16KB)
  bf16* WT0 = (bf16*)(smem + 65536 + 16384);     // 256 x 64 tile       (32KB)
  bf16* WT1 = (bf16*)(smem + 65536 + 16384 + 32768);  //                (32KB)
  __shared__ int okS, doCS;

  const int tid = threadIdx.x;
  const int lane = tid & 63;
  const int wave = tid >> 6;
  const int l15 = lane & 15;
  const int kg = lane >> 4;
  const int xorv = (l15 & 7) << 4;        // byte XOR for swizzled reads
  const int sr = wave * 8 + (lane >> 3);  // staging row within 32-row round
  const int cbE = (lane & 7) * 8;         // staging col element offset
  const int strip = blockIdx.x & (NSTR - 1);
  const int rb = blockIdx.x >> 4;

  // b1 slice for this thread's output columns (constant across phases)
  float bReg[4];
#pragma unroll
  for (int ni = 0; ni < 4; ++ni)
    bReg[ni] = b1[strip * SW + wave * 64 + ni * 16 + l15];

  auto stageW = [&](bf16* buf, int ti2) {
#pragma unroll
    for (int i = 0; i < 8; ++i) {
      const bf16* g;
      if (ti2 < 16) {
        g = W1bT + (size_t)(strip * SW + i * 32 + sr) * NH + ti2 * 64 + cbE;
      } else {
        const int tj = ti2 - 16;
        g = W2bT + (size_t)((tj >> 2) * 256 + i * 32 + sr) * NOH + strip * SW +
            (tj & 3) * 64 + cbE;
      }
      __builtin_amdgcn_global_load_lds(
          (const __attribute__((address_space(1))) void*)g,
          (__attribute__((address_space(3))) void*)&buf[(i * 32 + wave * 8) * 64],
          16, 0, 0);
    }
  };

  f32x4 acc[2][4];
  auto zacc = [&] {
#pragma unroll
    for (int mf = 0; mf < 2; ++mf)
#pragma unroll
      for (int ni = 0; ni < 4; ++ni) acc[mf][ni] = f32x4{0.f, 0.f, 0.f, 0.f};
  };

  // one BK=64 tile of MFMA from swizzled LDS A-operand + staged W tile
  auto tileMM = [&](const char* Abase, int rstride, int kbyteBase, const bf16* wt) {
#pragma unroll
    for (int ks = 0; ks < 64; ks += 32) {
      const int kb = kbyteBase + ks * 2 + kg * 16;
      bf16x8 af0 = *(const bf16x8*)(Abase + l15 * rstride + (kb ^ xorv));
      bf16x8 af1 = *(const bf16x8*)(Abase + (l15 + 16) * rstride + (kb ^ xorv));
      const int wofs = ks * 2 + kg * 16;
#pragma unroll
      for (int ni = 0; ni < 4; ++ni) {
        const int nl = wave * 64 + ni * 16 + l15;
        bf16x8 bw = *(const bf16x8*)((const char*)wt + nl * 128 + (wofs ^ xorv));
        acc[0][ni] = __builtin_amdgcn_mfma_f32_16x16x32_bf16(af0, bw, acc[0][ni], 0, 0, 0);
        acc[1][ni] = __builtin_amdgcn_mfma_f32_16x16x32_bf16(af1, bw, acc[1][ni], 0, 0, 0);
      }
    }
  };

  const unsigned long long* ybU = (const unsigned long long*)yb + (size_t)rb * 8192;
  unsigned long long* pU = (unsigned long long*)part;

#pragma unroll 1
  for (int p = 0; p < PHASES; ++p) {
    const int t = p >> 2, s = (p & 3) + 1;

    // ---- wait for yb generation p (relaxed spin: no cache maintenance) ----
    if (tid == 0) {
      int good = 1;
      long spins = 0;
      while (AL(&sy[FLAG_OFF + rb]) < (unsigned)p) {
        __builtin_amdgcn_s_sleep(2);
        if ((++spins & 255) == 0 && AL(&sy[ABT_OFF])) { good = 0; break; }
        if (spins > (1L << 22)) { AS(&sy[ABT_OFF], 1u); good = 0; break; }
      }
      okS = good;
    }
    __syncthreads();
    if (!okS) return;

    // ---- stage yb rows into swizzled LDS (coherent sc1 loads) ----
#pragma unroll
    for (int j = 0; j < 16; ++j) {
      const int u = j * 256 + tid;           // 16B unit: row = u>>7, ku = u&127
      const int row = u >> 7, ku = u & 127;
      unsigned long long a = AL(ybU + (size_t)u * 2);
      unsigned long long b = AL(ybU + (size_t)u * 2 + 1);
      char* d = (char*)YB + row * 2048 + ((ku * 16) ^ ((row & 7) << 4));
      ((unsigned long long*)d)[0] = a;
      ((unsigned long long*)d)[1] = b;
    }
    stageW(WT0, 0);
    __syncthreads();

    // ---- GEMM-A: acc = yb @ W1strip, 16 tiles ----
    zacc();
    bf16* cur = WT0; bf16* nxt = WT1;
#pragma unroll 1
    for (int ti = 0; ti < 16; ++ti) {
      stageW(nxt, ti + 1);  // ti=15 stages first W2 tile
      tileMM((const char*)YB, 2048, ti * 128, cur);
      __syncthreads();
      { bf16* tmp = cur; cur = nxt; nxt = tmp; }
    }
    // epilogue A: Hs = bf16(tanh(acc + b1)), swizzled
#pragma unroll
    for (int mf = 0; mf < 2; ++mf)
#pragma unroll
      for (int ni = 0; ni < 4; ++ni) {
        const int colb = (wave * 64 + ni * 16 + l15) * 2;
#pragma unroll
        for (int j = 0; j < 4; ++j) {
          const int row = mf * 16 + kg * 4 + j;
          const float v = tanhf(acc[mf][ni][j] + bReg[ni]);
          *(bf16*)((char*)Hs + row * 512 + (colb ^ ((row & 7) << 4))) =
              __float2bfloat16(v);
        }
      }
    __syncthreads();  // Hs visible to all waves

    // ---- GEMM-B: part += Hs @ W2strip, 4 n-halves x 4 k-tiles ----
    zacc();
    float* pb = part + ((size_t)(strip >> 1) * NRB + rb) * (size_t)(R * NH);
#pragma unroll 1
    for (int tj = 0; tj < 16; ++tj) {
      if (tj + 1 < 16) stageW(nxt, tj + 17);
      tileMM((const char*)Hs, 512, (tj & 3) * 128, cur);
      __syncthreads();
      { bf16* tmp = cur; cur = nxt; nxt = tmp; }
      if ((tj & 3) == 3) {
        const int hb = tj >> 2;
#pragma unroll
        for (int mf = 0; mf < 2; ++mf)
#pragma unroll
          for (int ni = 0; ni < 4; ++ni) {
            const int col = hb * 256 + wave * 64 + ni * 16 + l15;
#pragma unroll
            for (int j = 0; j < 4; ++j) {
              const int row = mf * 16 + kg * 4 + j;
              atomicAdd(&pb[row * 1024 + col], acc[mf][ni][j]);
              acc[mf][ni][j] = 0.f;
            }
          }
      }
    }

    // ---- arrive; last two arrivers each run half the RK4 combine ----
    __syncthreads();  // drain atomicAdds (vmcnt0 at barrier)
    if (tid == 0) {
      unsigned r = AFA(&sy[CNT_OFF + p * NRB + rb], 1u);
      doCS = (r >= (unsigned)(NSTR - 2)) ? (int)(r - (NSTR - 2)) + 1 : 0;
    }
    __syncthreads();
    if (doCS) {
      const int hc = doCS - 1;  // which 16-row half
      const float dtv = ts[t + 1] - ts[t];
#pragma unroll 2
      for (int jj = 0; jj < 32; ++jj) {
        const int e2 = hc * 8192 + jj * 256 + tid;  // f32-pair index in slice
        float lo = 0.f, hi = 0.f;
#pragma unroll
        for (int sg = 0; sg < 8; ++sg) {
          unsigned long long* ap = pU + ((size_t)(sg * NRB + rb) * 16384 + e2);
          unsigned long long v = AL(ap);
          AS(ap, 0ull);  // re-zero for next phase
          lo += lo32f(v);
          hi += hi32f(v);
        }
        const int col = (e2 * 2) & (NH - 1);
        lo += b2[col];
        hi += b2[col + 1];
        const size_t pi = (size_t)rb * 16384 + e2;
        unsigned long long yv = AL((unsigned long long*)y + pi);
        const float ylo = lo32f(yv), yhi = hi32f(yv);
        float nlo, nhi;
        if (s == 1) {
          AS((unsigned long long*)k1 + pi, packf2(lo, hi));
          nlo = ylo + lo * (dtv / 3.0f);
          nhi = yhi + hi * (dtv / 3.0f);
        } else if (s == 2) {
          unsigned long long k1v = AL((unsigned long long*)k1 + pi);
          AS((unsigned long long*)k2 + pi, packf2(lo, hi));
          nlo = ylo + (lo - lo32f(k1v) * (1.0f / 3.0f)) * dtv;
          nhi = yhi + (hi - hi32f(k1v) * (1.0f / 3.0f)) * dtv;
        } else if (s == 3) {
          unsigned long long k1v = AL((unsigned long long*)k1 + pi);
          unsigned long long k2v = AL((unsigned long long*)k2 + pi);
          AS((unsigned long long*)k3 + pi, packf2(lo, hi));
          nlo = ylo + (lo32f(k1v) - lo32f(k2v) + lo) * dtv;
          nhi = yhi + (hi32f(k1v) - hi32f(k2v) + hi) * dtv;
        } else {
          unsigned long long k1v = AL((unsigned long long*)k1 + pi);
          unsigned long long k2v = AL((unsigned long long*)k2 + pi);
          unsigned long long k3v = AL((unsigned long long*)k3 + pi);
          nlo = ylo + (lo32f(k1v) + 3.0f * (lo32f(k2v) + lo32f(k3v)) + lo) * (dtv * 0.125f);
          nhi = yhi + (hi32f(k1v) + 3.0f * (hi32f(k2v) + hi32f(k3v)) + hi) * (dtv * 0.125f);
          AS((unsigned long long*)y + pi, packf2(nlo, nhi));
          ((unsigned*)pred)[(size_t)(t + 1) * (NB * NH / 2) + pi] = packbf(nlo, nhi);
        }
        AS((unsigned*)yb + pi, packbf(nlo, nhi));
      }
      __syncthreads();  // drain this half's stores
      if (tid == 0) {
        unsigned d = AFA(&sy[CD_OFF + p * NRB + rb], 1u);
        if (d == 1) AS(&sy[FLAG_OFF + rb], (unsigned)(p + 1));
      }
    }
  }
}

// ---------------------------------------------------------------------------
// Final projection GEMM: 128x128 tile, dbuf prefetch.  out = A @ BT^T + bias
// ---------------------------------------------------------------------------
__global__ __launch_bounds__(256) void proj_gemm(
    const bf16* __restrict__ A, const bf16* __restrict__ BT,
    int M, int N, int K, const float* __restrict__ bias,
    float* __restrict__ outF) {
  constexpr int TM = 128, TN = 128;

  __shared__ __align__(16) bf16 As[2][TM * 64];
  __shared__ __align__(16) bf16 Bs[2][TN * 64];

  const int tid = threadIdx.x;
  const int lane = tid & 63;
  const int wave = tid >> 6;
  const int wr = wave >> 1;
  const int wc = wave & 1;
  const int row0 = blockIdx.y * TM;
  const int col0 = blockIdx.x * TN;
  const int l15 = lane & 15;
  const int kg = lane >> 4;
  const int sr = wave * 8 + (lane >> 3);
  const int cb = (lane & 7) * 8;

  f32x4 acc[4][4] = {};

  auto stage = [&](int buf, int kt) {
#pragma unroll
    for (int i = 0; i < 4; ++i) {
      const bf16* ga = A + (size_t)(row0 + i * 32 + sr) * K + kt + cb;
      __builtin_amdgcn_global_load_lds(
          (const __attribute__((address_space(1))) void*)ga,
          (__attribute__((address_space(3))) void*)&As[buf][(i * 32 + wave * 8) * 64],
          16, 0, 0);
      const bf16* gb = BT + (size_t)(col0 + i * 32 + sr) * K + kt + cb;
      __builtin_amdgcn_global_load_lds(
          (const __attribute__((address_space(1))) void*)gb,
          (__attribute__((address_space(3))) void*)&Bs[buf][(i * 32 + wave * 8) * 64],
          16, 0, 0);
    }
  };

  stage(0, 0);
  __syncthreads();
  int cur = 0;

  for (int kt = 0; kt < K; kt += 64) {
    if (kt + 64 < K) stage(cur ^ 1, kt + 64);
#pragma unroll
    for (int ks = 0; ks < 64; ks += 32) {
      bf16x8 af[4], bfr[4];
      const int kb = ks + kg * 8;
#pragma unroll
      for (int mi = 0; mi < 4; ++mi)
        af[mi] = *reinterpret_cast<const bf16x8*>(
            &As[cur][(wr * 64 + mi * 16 + l15) * 64 + kb]);
#pragma unroll
      for (int ni = 0; ni < 4; ++ni)
        bfr[ni] = *reinterpret_cast<const bf16x8*>(
            &Bs[cur][(wc * 64 + ni * 16 + l15) * 64 + kb]);
#pragma unroll
      for (int mi = 0; mi < 4; ++mi)
#pragma unroll
        for (int ni = 0; ni < 4; ++ni)
          acc[mi][ni] = __builtin_amdgcn_mfma_f32_16x16x32_bf16(
              af[mi], bfr[ni], acc[mi][ni], 0, 0, 0);
    }
    __syncthreads();
    cur ^= 1;
  }

#pragma unroll
  for (int mi = 0; mi < 4; ++mi) {
    const int grow_base = row0 + wr * 64 + mi * 16 + kg * 4;
#pragma unroll
    for (int ni = 0; ni < 4; ++ni) {
      const int gcol = col0 + wc * 64 + ni * 16 + l15;
#pragma unroll
      for (int j = 0; j < 4; ++j)
        outF[(size_t)(grow_base + j) * N + gcol] = acc[mi][ni][j] + bias[gcol];
    }
  }
}

// ---------------------------------------------------------------------------
// In-place row softmax over C=512; one wave per row.
// ---------------------------------------------------------------------------
__global__ void softmax_rows(float* __restrict__ out) {
  const int row = blockIdx.x * 4 + (threadIdx.x >> 6);
  const int lane = threadIdx.x & 63;
  float* p = out + (size_t)row * NC + lane * 8;
  f32x4 a = *reinterpret_cast<const f32x4*>(p);
  f32x4 b = *reinterpret_cast<const f32x4*>(p + 4);

  float m = fmaxf(fmaxf(fmaxf(a[0], a[1]), fmaxf(a[2], a[3])),
                  fmaxf(fmaxf(b[0], b[1]), fmaxf(b[2], b[3])));
#pragma unroll
  for (int off = 32; off > 0; off >>= 1) m = fmaxf(m, __shfl_xor(m, off));

  f32x4 ea, eb;
  float sum = 0.0f;
#pragma unroll
  for (int j = 0; j < 4; ++j) { ea[j] = expf(a[j] - m); sum += ea[j]; }
#pragma unroll
  for (int j = 0; j < 4; ++j) { eb[j] = expf(b[j] - m); sum += eb[j]; }
#pragma unroll
  for (int off = 32; off > 0; off >>= 1) sum += __shfl_xor(sum, off);

  const float inv = 1.0f / sum;
  ea *= inv;
  eb *= inv;
  *reinterpret_cast<f32x4*>(p) = ea;
  *reinterpret_cast<f32x4*>(p + 4) = eb;
}

// ---------------------------------------------------------------------------
extern "C" void kernel_launch(void* const* d_in, const int* in_sizes, int n_in,
                              void* d_out, int out_size, void* d_ws, size_t ws_size,
                              hipStream_t stream) {
  const float* z = (const float*)d_in[0];
  const float* ts = (const float*)d_in[1];
  const float* W1 = (const float*)d_in[2];
  const float* b1 = (const float*)d_in[3];
  const float* W2 = (const float*)d_in[4];
  const float* b2 = (const float*)d_in[5];
  const float* Wf = (const float*)d_in[6];
  const float* bfv = (const float*)d_in[7];

  char* w = (char*)d_ws;
  bf16* W1bT = (bf16*)w;          w += (size_t)NOH * NH * 2;          // 8 MB
  bf16* W2bT = (bf16*)w;          w += (size_t)NH * NOH * 2;          // 8 MB
  bf16* WfT  = (bf16*)w;          w += (size_t)NC * NH * 2;           // 1 MB
  float* y   = (float*)w;         w += (size_t)NB * NH * 4;           // 2 MB
  bf16* yb   = (bf16*)w;          w += (size_t)NB * NH * 2;           // 1 MB
  float* k1  = (float*)w;         w += (size_t)NB * NH * 4;
  float* k2  = (float*)w;         w += (size_t)NB * NH * 4;
  float* k3  = (float*)w;         w += (size_t)NB * NH * 4;           // 6 MB
  float* part = (float*)w;        w += (size_t)8 * NB * NH * 4;       // 16 MB
  bf16* pred = (bf16*)w;          w += (size_t)NT * NB * NH * 2;      // 40 MB
  unsigned* sy = (unsigned*)w;    w += (size_t)SYNC_WORDS * 4;        // 20 KB

  float* logits = (float*)d_out;  // [NT*NB, NC] fp32, softmaxed in place

  // Weight transpose-casts (W1/W2 with baked LDS swizzle) + state/sync init
  transpose_cast<true><<<dim3(NOH / 32, NH / 32), dim3(32, 8), 0, stream>>>(W1, W1bT, NH, NOH);
  transpose_cast<true><<<dim3(NH / 32, NOH / 32), dim3(32, 8), 0, stream>>>(W2, W2bT, NOH, NH);
  transpose_cast<false><<<dim3(NC / 32, NH / 32), dim3(32, 8), 0, stream>>>(Wf, WfT, NH, NC);
  init_state<<<(NB * NH) / 256, 256, 0, stream>>>(z, y, yb, pred, part, sy);

  // Entire RK4 loop: one persistent kernel, rowblock-local flag pipeline
  hipFuncSetAttribute((const void*)ode_pipeline,
                      hipFuncAttributeMaxDynamicSharedMemorySize, 147456);
  ode_pipeline<<<dim3(NRB * NSTR), dim3(256), 147456, stream>>>(
      W1bT, W2bT, b1, b2, ts, y, yb, k1, k2, k3, part, pred, sy);

  // logits = pred @ Wf + bf   [20480 x 512], then softmax
  proj_gemm<<<dim3(NC / 128, (NT * NB) / 128), 256, 0, stream>>>(
      pred, WfT, NT * NB, NC, NH, bfv, logits);
  softmax_rows<<<(NT * NB) / 4, 256, 0, stream>>>(logits);
}

// Round 7
// 5893.028 us; speedup vs baseline: 10.0021x; 5.7923x over previous
//
#include <hip/hip_runtime.h>
#include <hip/hip_bf16.h>
#include <math.h>

using bf16 = __hip_bfloat16;
typedef __bf16 bf16x8 __attribute__((ext_vector_type(8)));
typedef float f32x4 __attribute__((ext_vector_type(4)));

// Problem dims
static constexpr int NB = 512, NH = 1024, NOH = 4096, NC = 512, NT = 40;

// All LDS-staged matrices are stored "chunk-swizzled": element (r,k) lives at
// r*K + (k ^ ((r&7)<<3))  -- the 8-element (16B) chunks within each 64-elem
// k-window are permuted by r&7.  global_load_lds then copies rows linearly
// (swizzle-preserving) and the GEMM fragment reads XOR the byte address with
// ((row&7)<<4), which undoes the permutation AND spreads the 16 fragment rows
// across 8 distinct 16B slots -> 2 lanes/bank (free) instead of 16-way.

// ---------------------------------------------------------------------------
// Transpose-cast fp32 (K x N) -> bf16 (N x K), chunk-swizzled.
// ---------------------------------------------------------------------------
__global__ void transpose_cast(const float* __restrict__ W, bf16* __restrict__ WT,
                               int K, int N) {
  __shared__ float tile[32][33];
  const int n0 = blockIdx.x * 32;
  const int k0 = blockIdx.y * 32;
  const int tx = threadIdx.x;  // 0..31
  const int ty = threadIdx.y;  // 0..7
#pragma unroll
  for (int i = 0; i < 4; ++i) {
    int r = ty + i * 8;
    tile[r][tx] = W[(size_t)(k0 + r) * N + n0 + tx];
  }
  __syncthreads();
#pragma unroll
  for (int i = 0; i < 4; ++i) {
    int r = ty + i * 8;
    const int n = n0 + r, k = k0 + tx;
    WT[(size_t)n * K + (k ^ ((n & 7) << 3))] = __float2bfloat16(tile[tx][r]);
  }
}

// ---------------------------------------------------------------------------
// Init: y = z (fp32), yb = pred[0] = bf16(z) (both chunk-swizzled).
// ---------------------------------------------------------------------------
__global__ void init_state(const float* __restrict__ z, float* __restrict__ y,
                           bf16* __restrict__ yb, bf16* __restrict__ pred0) {
  const int i = blockIdx.x * 256 + threadIdx.x;
  const int r = i >> 10, c = i & (NH - 1);
  float v = z[i];
  y[i] = v;
  bf16 b = __float2bfloat16(v);
  const int sw = r * NH + (c ^ ((r & 7) << 3));
  yb[sw] = b;
  pred0[sw] = b;
}

// ---------------------------------------------------------------------------
// bf16 GEMM, B pre-transposed (N x K), both operands chunk-swizzled.
// TM x TN tile, 4 waves (2x2), BK-step double-buffered gload_lds pipeline.
// EPI 0 (GEMM1):  h = bf16(tanh(acc + b1[col]))              (swizzled store)
// EPI 1 (GEMM2+RK4): v = acc + b2[col]; full 3/8-rule stage algebra:
//     s=1: k1=v, yn = y + v*dt/3
//     s=2: k2=v, yn = y + (v - k1/3)*dt
//     s=3: k3=v, yn = y + (k1 - k2 + v)*dt
//     s=4: yn = y + (k1 + 3(k2+k3) + v)*dt/8; y=yn; pred[t+1]=bf16(yn)
//     always: yb = bf16(yn)                                  (swizzled store)
// EPI 2 (proj):  outF = acc + bias[col]                      (plain store)
// ---------------------------------------------------------------------------
template <int TM, int TN, int BK, int EPI>
__global__ __launch_bounds__(256, (EPI == 2) ? 1 : 2) void gemm_bt(
    const bf16* __restrict__ A, const bf16* __restrict__ BT,
    int M, int N, int K, const float* __restrict__ bias,
    bf16* __restrict__ outB, float* __restrict__ outF,
    float* __restrict__ y, bf16* __restrict__ yb,
    float* __restrict__ k1, float* __restrict__ k2, float* __restrict__ k3,
    bf16* __restrict__ pred, const float* __restrict__ ts, int t, int s) {
  constexpr int MF = TM / 32;       // row fragments per wave
  constexpr int NF = TN / 32;       // col fragments per wave
  constexpr int CB = BK / 8;        // 16B chunks per row
  constexpr int RPR = 256 / CB;     // rows per 4KB staging round
  constexpr int RA = TM / RPR;
  constexpr int RB = TN / RPR;

  __shared__ __align__(16) bf16 As[2][TM * BK];
  __shared__ __align__(16) bf16 Bs[2][TN * BK];

  const int tid = threadIdx.x;
  const int lane = tid & 63;
  const int wave = tid >> 6;
  const int wr = wave >> 1, wc = wave & 1;
  const int row0 = blockIdx.y * TM, col0 = blockIdx.x * TN;
  const int l15 = lane & 15, kg = lane >> 4;
  const int xorB = (l15 & 7) << 4;   // fragment-read byte XOR
  const int srow = tid / CB;         // staging row within round
  const int scol = (tid % CB) * 8;   // staging elem offset

  f32x4 acc[MF][NF] = {};

  auto stage = [&](int buf, int kt) {
#pragma unroll
    for (int i = 0; i < RA; ++i) {
      const bf16* g = A + (size_t)(row0 + i * RPR + srow) * K + kt + scol;
      __builtin_amdgcn_global_load_lds(
          (const __attribute__((address_space(1))) void*)g,
          (__attribute__((address_space(3))) void*)&As[buf][i * 2048 + tid * 8],
          16, 0, 0);
    }
#pragma unroll
    for (int i = 0; i < RB; ++i) {
      const bf16* g = BT + (size_t)(col0 + i * RPR + srow) * K + kt + scol;
      __builtin_amdgcn_global_load_lds(
          (const __attribute__((address_space(1))) void*)g,
          (__attribute__((address_space(3))) void*)&Bs[buf][i * 2048 + tid * 8],
          16, 0, 0);
    }
  };

  stage(0, 0);
  __syncthreads();
  int cur = 0;

  for (int kt = 0; kt < K; kt += BK) {
    if (kt + BK < K) stage(cur ^ 1, kt + BK);  // prefetch next K-tile
#pragma unroll
    for (int ks = 0; ks < BK; ks += 32) {
      bf16x8 af[MF], bfr[NF];
      const int kb2 = (ks + kg * 8) * 2;  // byte offset of k within row
#pragma unroll
      for (int mi = 0; mi < MF; ++mi) {
        const int r = wr * (TM / 2) + mi * 16 + l15;
        af[mi] = *reinterpret_cast<const bf16x8*>(
            (const char*)&As[cur][0] + ((r * BK * 2 + kb2) ^ xorB));
      }
#pragma unroll
      for (int ni = 0; ni < NF; ++ni) {
        const int r = wc * (TN / 2) + ni * 16 + l15;
        bfr[ni] = *reinterpret_cast<const bf16x8*>(
            (const char*)&Bs[cur][0] + ((r * BK * 2 + kb2) ^ xorB));
      }
#pragma unroll
      for (int mi = 0; mi < MF; ++mi)
#pragma unroll
        for (int ni = 0; ni < NF; ++ni)
          acc[mi][ni] = __builtin_amdgcn_mfma_f32_16x16x32_bf16(
              af[mi], bfr[ni], acc[mi][ni], 0, 0, 0);
    }
    __syncthreads();  // prefetched tile ready (vmcnt drain at barrier)
    cur ^= 1;
  }

  // Epilogue.  C/D layout: col = lane&15, row = (lane>>4)*4 + reg
  const float dtv = (EPI == 1) ? (ts[t + 1] - ts[t]) : 0.0f;
#pragma unroll
  for (int mi = 0; mi < MF; ++mi) {
    const int gr0 = row0 + wr * (TM / 2) + mi * 16 + kg * 4;
#pragma unroll
    for (int ni = 0; ni < NF; ++ni) {
      const int gcol = col0 + wc * (TN / 2) + ni * 16 + l15;
      const float b = bias[gcol];
#pragma unroll
      for (int j = 0; j < 4; ++j) {
        const int r = gr0 + j;
        const float v = acc[mi][ni][j] + b;
        if constexpr (EPI == 0) {
          outB[(size_t)r * N + (gcol ^ ((r & 7) << 3))] =
              __float2bfloat16(tanhf(v));
        } else if constexpr (EPI == 1) {
          const size_t idx = (size_t)r * N + gcol;
          float yn;
          if (s == 1) {
            k1[idx] = v;
            yn = y[idx] + v * (dtv / 3.0f);
          } else if (s == 2) {
            k2[idx] = v;
            yn = y[idx] + (v - k1[idx] * (1.0f / 3.0f)) * dtv;
          } else if (s == 3) {
            k3[idx] = v;
            yn = y[idx] + (k1[idx] - k2[idx] + v) * dtv;
          } else {
            yn = y[idx] + (k1[idx] + 3.0f * (k2[idx] + k3[idx]) + v) * (dtv * 0.125f);
            y[idx] = yn;
            pred[(size_t)(t + 1) * (NB * NH) + (size_t)r * N +
                 (gcol ^ ((r & 7) << 3))] = __float2bfloat16(yn);
          }
          yb[(size_t)r * N + (gcol ^ ((r & 7) << 3))] = __float2bfloat16(yn);
        } else {
          outF[(size_t)r * N + gcol] = v;
        }
      }
    }
  }
}

// ---------------------------------------------------------------------------
// In-place row softmax over C=512; one wave per row.
// ---------------------------------------------------------------------------
__global__ void softmax_rows(float* __restrict__ out) {
  const int row = blockIdx.x * 4 + (threadIdx.x >> 6);
  const int lane = threadIdx.x & 63;
  float* p = out + (size_t)row * NC + lane * 8;
  f32x4 a = *reinterpret_cast<const f32x4*>(p);
  f32x4 b = *reinterpret_cast<const f32x4*>(p + 4);

  float m = fmaxf(fmaxf(fmaxf(a[0], a[1]), fmaxf(a[2], a[3])),
                  fmaxf(fmaxf(b[0], b[1]), fmaxf(b[2], b[3])));
#pragma unroll
  for (int off = 32; off > 0; off >>= 1) m = fmaxf(m, __shfl_xor(m, off));

  f32x4 ea, eb;
  float sum = 0.0f;
#pragma unroll
  for (int j = 0; j < 4; ++j) { ea[j] = expf(a[j] - m); sum += ea[j]; }
#pragma unroll
  for (int j = 0; j < 4; ++j) { eb[j] = expf(b[j] - m); sum += eb[j]; }
#pragma unroll
  for (int off = 32; off > 0; off >>= 1) sum += __shfl_xor(sum, off);

  const float inv = 1.0f / sum;
  ea *= inv;
  eb *= inv;
  *reinterpret_cast<f32x4*>(p) = ea;
  *reinterpret_cast<f32x4*>(p + 4) = eb;
}

// ---------------------------------------------------------------------------
extern "C" void kernel_launch(void* const* d_in, const int* in_sizes, int n_in,
                              void* d_out, int out_size, void* d_ws, size_t ws_size,
                              hipStream_t stream) {
  const float* z = (const float*)d_in[0];
  const float* ts = (const float*)d_in[1];
  const float* W1 = (const float*)d_in[2];
  const float* b1 = (const float*)d_in[3];
  const float* W2 = (const float*)d_in[4];
  const float* b2 = (const float*)d_in[5];
  const float* Wf = (const float*)d_in[6];
  const float* bfv = (const float*)d_in[7];

  char* w = (char*)d_ws;
  bf16* W1bT = (bf16*)w;          w += (size_t)NOH * NH * 2;     // 8 MB
  bf16* W2bT = (bf16*)w;          w += (size_t)NH * NOH * 2;     // 8 MB
  bf16* WfT  = (bf16*)w;          w += (size_t)NC * NH * 2;      // 1 MB
  float* y   = (float*)w;         w += (size_t)NB * NH * 4;      // 2 MB
  bf16* yb   = (bf16*)w;          w += (size_t)NB * NH * 2;      // 1 MB
  float* k1  = (float*)w;         w += (size_t)NB * NH * 4;
  float* k2  = (float*)w;         w += (size_t)NB * NH * 4;
  float* k3  = (float*)w;         w += (size_t)NB * NH * 4;      // 6 MB
  bf16* h    = (bf16*)w;          w += (size_t)NB * NOH * 2;     // 4 MB
  bf16* pred = (bf16*)w;          w += (size_t)NT * NB * NH * 2; // 40 MB

  float* logits = (float*)d_out;  // [NT*NB, NC] fp32, softmaxed in place

  // Weight transpose-casts (chunk-swizzled) + state init (stateless)
  transpose_cast<<<dim3(NOH / 32, NH / 32), dim3(32, 8), 0, stream>>>(W1, W1bT, NH, NOH);
  transpose_cast<<<dim3(NH / 32, NOH / 32), dim3(32, 8), 0, stream>>>(W2, W2bT, NOH, NH);
  transpose_cast<<<dim3(NC / 32, NH / 32), dim3(32, 8), 0, stream>>>(Wf, WfT, NH, NC);
  init_state<<<(NB * NH) / 256, 256, 0, stream>>>(z, y, yb, pred);

  for (int t = 0; t < NT - 1; ++t) {
    for (int s = 1; s <= 4; ++s) {
      // GEMM1: h = tanh(yb @ W1 + b1)  [512 x 4096], 64x64xBK128, 512 WGs
      gemm_bt<64, 64, 128, 0><<<dim3(NOH / 64, NB / 64), 256, 0, stream>>>(
          yb, W1bT, NB, NOH, NH, b1, h, nullptr,
          nullptr, nullptr, nullptr, nullptr, nullptr, nullptr, nullptr, 0, 0);
      // GEMM2 + fused RK4 stage: [512 x 1024] over K=4096, 32x32xBK128, 512 WGs
      gemm_bt<32, 32, 128, 1><<<dim3(NH / 32, NB / 32), 256, 0, stream>>>(
          h, W2bT, NB, NH, NOH, b2, nullptr, nullptr,
          y, yb, k1, k2, k3, pred, ts, t, s);
    }
  }

  // logits = pred @ Wf + bf   [20480 x 512], then softmax
  gemm_bt<128, 128, 64, 2><<<dim3(NC / 128, (NT * NB) / 128), 256, 0, stream>>>(
      pred, WfT, NT * NB, NC, NH, bfv, nullptr, logits,
      nullptr, nullptr, nullptr, nullptr, nullptr, nullptr, nullptr, 0, 0);
  softmax_rows<<<(NT * NB) / 4, 256, 0, stream>>>(logits);
}

// Round 8
// 4922.156 us; speedup vs baseline: 11.9750x; 1.1972x over previous
//
#include <hip/hip_runtime.h>
#include <hip/hip_bf16.h>
#include <math.h>

using bf16 = __hip_bfloat16;
typedef __bf16 bf16x8 __attribute__((ext_vector_type(8)));
typedef float f32x4 __attribute__((ext_vector_type(4)));

// Problem dims
static constexpr int NB = 512, NH = 1024, NOH = 4096, NC = 512, NT = 40;
static constexpr int SPLITK = 4;

// All LDS-staged matrices are "chunk-swizzled": element (r,k) stored at
// r*K + (k ^ ((r&7)<<3)).  global_load_lds copies rows linearly (swizzle-
// preserving); fragment reads XOR the byte address with ((l15&7)<<4), undoing
// the permutation and spreading 16 fragment rows over 8 bank groups.

// ---------------------------------------------------------------------------
// Transpose-cast fp32 (K x N) -> bf16 (N x K), chunk-swizzled.
// ---------------------------------------------------------------------------
__global__ void transpose_cast(const float* __restrict__ W, bf16* __restrict__ WT,
                               int K, int N) {
  __shared__ float tile[32][33];
  const int n0 = blockIdx.x * 32;
  const int k0 = blockIdx.y * 32;
  const int tx = threadIdx.x;
  const int ty = threadIdx.y;
#pragma unroll
  for (int i = 0; i < 4; ++i) {
    int r = ty + i * 8;
    tile[r][tx] = W[(size_t)(k0 + r) * N + n0 + tx];
  }
  __syncthreads();
#pragma unroll
  for (int i = 0; i < 4; ++i) {
    int r = ty + i * 8;
    const int n = n0 + r, k = k0 + tx;
    WT[(size_t)n * K + (k ^ ((n & 7) << 3))] = __float2bfloat16(tile[tx][r]);
  }
}

// ---------------------------------------------------------------------------
// Init: y = z (fp32), yb = pred[0] = bf16(z) (chunk-swizzled).
// ---------------------------------------------------------------------------
__global__ void init_state(const float* __restrict__ z, float* __restrict__ y,
                           bf16* __restrict__ yb, bf16* __restrict__ pred0) {
  const int i = blockIdx.x * 256 + threadIdx.x;
  const int r = i >> 10, c = i & (NH - 1);
  float v = z[i];
  y[i] = v;
  bf16 b = __float2bfloat16(v);
  const int sw = r * NH + (c ^ ((r & 7) << 3));
  yb[sw] = b;
  pred0[sw] = b;
}

// ---------------------------------------------------------------------------
// Stage GEMM: 64x64 tile, BK=64, K-chunk=1024 (16 iters), 4 waves (2x2).
// 4 LDS buffers, 3-deep prefetch, ONE raw s_barrier per iter with counted
// s_waitcnt vmcnt(8/4/0) -- two SIs (8 loads) stay in flight across barriers.
// XCD-aware decode: xcd = bid&7; output columns partitioned so each XCD's L2
// only fills 1MB of the weight matrix per stage.
// EPI 0 (GEMM1): h = bf16(tanh(acc + b1[col]))   [512x4096], swizzled store
// EPI 1 (GEMM2): part[kz] = acc (fp32 partials)  [4 x 512x1024]
// ---------------------------------------------------------------------------
template <int EPI>
__global__ __launch_bounds__(256, 2) void gemm_stage(
    const bf16* __restrict__ A, const bf16* __restrict__ BT,
    const float* __restrict__ bias, bf16* __restrict__ outB,
    float* __restrict__ outF) {
  constexpr int BK = 64;
  constexpr int KCH = 1024;
  constexpr int KST = (EPI == 0) ? NH : NOH;   // operand row stride
  constexpr int NOUT = (EPI == 0) ? NOH : NH;  // output row stride
  constexpr int NI = KCH / BK;                 // 16 K-iterations

  __shared__ __align__(16) bf16 As[4][64 * BK];  // 32 KB
  __shared__ __align__(16) bf16 Bs[4][64 * BK];  // 32 KB

  const int tid = threadIdx.x;
  const int lane = tid & 63;
  const int wave = tid >> 6;
  const int wr = wave >> 1, wc = wave & 1;
  const int l15 = lane & 15, kg = lane >> 4;
  const int xorB = (l15 & 7) << 4;
  const int srow = tid >> 3;         // staging row within 32-row round
  const int scol = (tid & 7) * 8;    // staging elem offset

  // XCD-aware task decode (blockIdx % 8 -> XCD round-robin assumption)
  const int bid = blockIdx.x;
  const int xcd = bid & 7, slot = bid >> 3;
  int row0, col0, kbeg;
  float* outFb = outF;
  if constexpr (EPI == 0) {
    col0 = (xcd + ((slot & 7) << 3)) * 64;  // 64 col strips, strip%8 == xcd
    row0 = (slot >> 3) * 64;                // 8 row blocks
    kbeg = 0;
  } else {
    col0 = (xcd + ((slot & 1) << 3)) * 64;  // 16 col strips, strip%8 == xcd
    const int kz = (slot >> 1) & 3;         // split-K slice
    row0 = (slot >> 3) * 64;                // 8 row blocks
    kbeg = kz * KCH;
    outFb = outF + (size_t)kz * (NB * NH);
  }

  f32x4 acc[2][2] = {};

  auto stage = [&](int buf, int kt) {
#pragma unroll
    for (int i = 0; i < 2; ++i) {
      const bf16* ga = A + (size_t)(row0 + i * 32 + srow) * KST + kt + scol;
      __builtin_amdgcn_global_load_lds(
          (const __attribute__((address_space(1))) void*)ga,
          (__attribute__((address_space(3))) void*)&As[buf][i * 2048 + tid * 8],
          16, 0, 0);
      const bf16* gb = BT + (size_t)(col0 + i * 32 + srow) * KST + kt + scol;
      __builtin_amdgcn_global_load_lds(
          (const __attribute__((address_space(1))) void*)gb,
          (__attribute__((address_space(3))) void*)&Bs[buf][i * 2048 + tid * 8],
          16, 0, 0);
    }
  };

  // Prologue: 3 K-tiles in flight (12 loads/wave outstanding).
  stage(0, kbeg);
  stage(1, kbeg + BK);
  stage(2, kbeg + 2 * BK);

#pragma unroll 1
  for (int j = 0; j < NI; ++j) {
    // Wait until SI(j) is complete; leave SI(j+1), SI(j+2) in flight.
    if (j < NI - 2)       asm volatile("s_waitcnt vmcnt(8)" ::: "memory");
    else if (j == NI - 2) asm volatile("s_waitcnt vmcnt(4)" ::: "memory");
    else                  asm volatile("s_waitcnt vmcnt(0)" ::: "memory");
    __builtin_amdgcn_s_barrier();
    __builtin_amdgcn_sched_barrier(0);
    // Issue SI(j+3) into buf (j+3)&3: its previous readers (iter j-1) have
    // all crossed this iteration's barrier -> no race.
    if (j + 3 < NI) stage((j + 3) & 3, kbeg + (j + 3) * BK);

    const char* Ab = (const char*)&As[j & 3][0];
    const char* Bb = (const char*)&Bs[j & 3][0];
#pragma unroll
    for (int ks = 0; ks < BK; ks += 32) {
      const int kb2 = (ks + kg * 8) * 2;
      bf16x8 af[2], bf_[2];
#pragma unroll
      for (int mi = 0; mi < 2; ++mi) {
        const int r = wr * 32 + mi * 16 + l15;
        af[mi] = *reinterpret_cast<const bf16x8*>(Ab + ((r * 128 + kb2) ^ xorB));
      }
#pragma unroll
      for (int ni = 0; ni < 2; ++ni) {
        const int r = wc * 32 + ni * 16 + l15;
        bf_[ni] = *reinterpret_cast<const bf16x8*>(Bb + ((r * 128 + kb2) ^ xorB));
      }
#pragma unroll
      for (int mi = 0; mi < 2; ++mi)
#pragma unroll
        for (int ni = 0; ni < 2; ++ni)
          acc[mi][ni] = __builtin_amdgcn_mfma_f32_16x16x32_bf16(
              af[mi], bf_[ni], acc[mi][ni], 0, 0, 0);
    }
  }

  // Epilogue.  C/D layout: col = lane&15, row = (lane>>4)*4 + reg
#pragma unroll
  for (int mi = 0; mi < 2; ++mi) {
    const int gr0 = row0 + wr * 32 + mi * 16 + kg * 4;
#pragma unroll
    for (int ni = 0; ni < 2; ++ni) {
      const int gcol = col0 + wc * 32 + ni * 16 + l15;
      float b = 0.0f;
      if constexpr (EPI == 0) b = bias[gcol];
#pragma unroll
      for (int j = 0; j < 4; ++j) {
        const int r = gr0 + j;
        if constexpr (EPI == 0) {
          outB[(size_t)r * NOUT + (gcol ^ ((r & 7) << 3))] =
              __float2bfloat16(tanhf(acc[mi][ni][j] + b));
        } else {
          outFb[(size_t)r * NOUT + gcol] = acc[mi][ni][j];
        }
      }
    }
  }
}

// ---------------------------------------------------------------------------
// Combine split-K partials + RK4 (3/8 rule) stage algebra.
// k_s = sum(part) + b2; yb (and pred at s=4) stored chunk-swizzled.
// ---------------------------------------------------------------------------
__global__ void combine_stage(const float* __restrict__ part,
                              const float* __restrict__ b2,
                              float* __restrict__ y, bf16* __restrict__ yb,
                              float* __restrict__ k1, float* __restrict__ k2,
                              float* __restrict__ k3, bf16* __restrict__ pred_next,
                              const float* __restrict__ ts, int t, int s) {
  const int i = blockIdx.x * 256 + threadIdx.x;  // f32x4 index
  const float dt = ts[t + 1] - ts[t];
  constexpr int NE = NB * NH;

  f32x4 sum = {};
#pragma unroll
  for (int z = 0; z < SPLITK; ++z)
    sum += *reinterpret_cast<const f32x4*>(part + (size_t)z * NE + (size_t)i * 4);

  const int col = (i * 4) & (NH - 1);
  const int row = (i * 4) >> 10;
  const f32x4 bb = *reinterpret_cast<const f32x4*>(b2 + col);
  const f32x4 ksv = sum + bb;
  const f32x4 yv = *reinterpret_cast<const f32x4*>(y + (size_t)i * 4);

  f32x4 ynext;
  if (s == 1) {
    *reinterpret_cast<f32x4*>(k1 + (size_t)i * 4) = ksv;
    ynext = yv + ksv * (dt / 3.0f);
  } else if (s == 2) {
    const f32x4 k1v = *reinterpret_cast<const f32x4*>(k1 + (size_t)i * 4);
    *reinterpret_cast<f32x4*>(k2 + (size_t)i * 4) = ksv;
    ynext = yv + (ksv - k1v * (1.0f / 3.0f)) * dt;
  } else if (s == 3) {
    const f32x4 k1v = *reinterpret_cast<const f32x4*>(k1 + (size_t)i * 4);
    const f32x4 k2v = *reinterpret_cast<const f32x4*>(k2 + (size_t)i * 4);
    *reinterpret_cast<f32x4*>(k3 + (size_t)i * 4) = ksv;
    ynext = yv + (k1v - k2v + ksv) * dt;
  } else {
    const f32x4 k1v = *reinterpret_cast<const f32x4*>(k1 + (size_t)i * 4);
    const f32x4 k2v = *reinterpret_cast<const f32x4*>(k2 + (size_t)i * 4);
    const f32x4 k3v = *reinterpret_cast<const f32x4*>(k3 + (size_t)i * 4);
    ynext = yv + (k1v + (k2v + k3v) * 3.0f + ksv) * (dt * 0.125f);
    *reinterpret_cast<f32x4*>(y + (size_t)i * 4) = ynext;
  }

  union { bf16 h[4]; unsigned long long u; } pk;
#pragma unroll
  for (int j = 0; j < 4; ++j) pk.h[j] = __float2bfloat16(ynext[j]);
  const size_t sw = (size_t)row * NH + (col ^ ((row & 7) << 3));
  *reinterpret_cast<unsigned long long*>(yb + sw) = pk.u;
  if (s == 4) *reinterpret_cast<unsigned long long*>(pred_next + sw) = pk.u;
}

// ---------------------------------------------------------------------------
// Final projection GEMM: 128x128 tile, BK=64, depth-1 dbuf (proven round 7).
// ---------------------------------------------------------------------------
__global__ __launch_bounds__(256, 1) void proj_gemm(
    const bf16* __restrict__ A, const bf16* __restrict__ BT,
    int M, int N, int K, const float* __restrict__ bias,
    float* __restrict__ outF) {
  __shared__ __align__(16) bf16 As[2][128 * 64];
  __shared__ __align__(16) bf16 Bs[2][128 * 64];

  const int tid = threadIdx.x;
  const int lane = tid & 63;
  const int wave = tid >> 6;
  const int wr = wave >> 1, wc = wave & 1;
  const int row0 = blockIdx.y * 128, col0 = blockIdx.x * 128;
  const int l15 = lane & 15, kg = lane >> 4;
  const int xorB = (l15 & 7) << 4;
  const int srow = tid >> 3;
  const int scol = (tid & 7) * 8;

  f32x4 acc[4][4] = {};

  auto stage = [&](int buf, int kt) {
#pragma unroll
    for (int i = 0; i < 4; ++i) {
      const bf16* ga = A + (size_t)(row0 + i * 32 + srow) * K + kt + scol;
      __builtin_amdgcn_global_load_lds(
          (const __attribute__((address_space(1))) void*)ga,
          (__attribute__((address_space(3))) void*)&As[buf][i * 2048 + tid * 8],
          16, 0, 0);
      const bf16* gb = BT + (size_t)(col0 + i * 32 + srow) * K + kt + scol;
      __builtin_amdgcn_global_load_lds(
          (const __attribute__((address_space(1))) void*)gb,
          (__attribute__((address_space(3))) void*)&Bs[buf][i * 2048 + tid * 8],
          16, 0, 0);
    }
  };

  stage(0, 0);
  __syncthreads();
  int cur = 0;

  for (int kt = 0; kt < K; kt += 64) {
    if (kt + 64 < K) stage(cur ^ 1, kt + 64);
#pragma unroll
    for (int ks = 0; ks < 64; ks += 32) {
      const int kb2 = (ks + kg * 8) * 2;
      bf16x8 af[4], bf_[4];
#pragma unroll
      for (int mi = 0; mi < 4; ++mi) {
        const int r = wr * 64 + mi * 16 + l15;
        af[mi] = *reinterpret_cast<const bf16x8*>(
            (const char*)&As[cur][0] + ((r * 128 + kb2) ^ xorB));
      }
#pragma unroll
      for (int ni = 0; ni < 4; ++ni) {
        const int r = wc * 64 + ni * 16 + l15;
        bf_[ni] = *reinterpret_cast<const bf16x8*>(
            (const char*)&Bs[cur][0] + ((r * 128 + kb2) ^ xorB));
      }
#pragma unroll
      for (int mi = 0; mi < 4; ++mi)
#pragma unroll
        for (int ni = 0; ni < 4; ++ni)
          acc[mi][ni] = __builtin_amdgcn_mfma_f32_16x16x32_bf16(
              af[mi], bf_[ni], acc[mi][ni], 0, 0, 0);
    }
    __syncthreads();
    cur ^= 1;
  }

#pragma unroll
  for (int mi = 0; mi < 4; ++mi) {
    const int gr0 = row0 + wr * 64 + mi * 16 + kg * 4;
#pragma unroll
    for (int ni = 0; ni < 4; ++ni) {
      const int gcol = col0 + wc * 64 + ni * 16 + l15;
      const float b = bias[gcol];
#pragma unroll
      for (int j = 0; j < 4; ++j)
        outF[(size_t)(gr0 + j) * N + gcol] = acc[mi][ni][j] + b;
    }
  }
}

// ---------------------------------------------------------------------------
// In-place row softmax over C=512; one wave per row.
// ---------------------------------------------------------------------------
__global__ void softmax_rows(float* __restrict__ out) {
  const int row = blockIdx.x * 4 + (threadIdx.x >> 6);
  const int lane = threadIdx.x & 63;
  float* p = out + (size_t)row * NC + lane * 8;
  f32x4 a = *reinterpret_cast<const f32x4*>(p);
  f32x4 b = *reinterpret_cast<const f32x4*>(p + 4);

  float m = fmaxf(fmaxf(fmaxf(a[0], a[1]), fmaxf(a[2], a[3])),
                  fmaxf(fmaxf(b[0], b[1]), fmaxf(b[2], b[3])));
#pragma unroll
  for (int off = 32; off > 0; off >>= 1) m = fmaxf(m, __shfl_xor(m, off));

  f32x4 ea, eb;
  float sum = 0.0f;
#pragma unroll
  for (int j = 0; j < 4; ++j) { ea[j] = expf(a[j] - m); sum += ea[j]; }
#pragma unroll
  for (int j = 0; j < 4; ++j) { eb[j] = expf(b[j] - m); sum += eb[j]; }
#pragma unroll
  for (int off = 32; off > 0; off >>= 1) sum += __shfl_xor(sum, off);

  const float inv = 1.0f / sum;
  ea *= inv;
  eb *= inv;
  *reinterpret_cast<f32x4*>(p) = ea;
  *reinterpret_cast<f32x4*>(p + 4) = eb;
}

// ---------------------------------------------------------------------------
extern "C" void kernel_launch(void* const* d_in, const int* in_sizes, int n_in,
                              void* d_out, int out_size, void* d_ws, size_t ws_size,
                              hipStream_t stream) {
  const float* z = (const float*)d_in[0];
  const float* ts = (const float*)d_in[1];
  const float* W1 = (const float*)d_in[2];
  const float* b1 = (const float*)d_in[3];
  const float* W2 = (const float*)d_in[4];
  const float* b2 = (const float*)d_in[5];
  const float* Wf = (const float*)d_in[6];
  const float* bfv = (const float*)d_in[7];

  char* w = (char*)d_ws;
  bf16* W1bT = (bf16*)w;          w += (size_t)NOH * NH * 2;          // 8 MB
  bf16* W2bT = (bf16*)w;          w += (size_t)NH * NOH * 2;          // 8 MB
  bf16* WfT  = (bf16*)w;          w += (size_t)NC * NH * 2;           // 1 MB
  float* y   = (float*)w;         w += (size_t)NB * NH * 4;           // 2 MB
  bf16* yb   = (bf16*)w;          w += (size_t)NB * NH * 2;           // 1 MB
  float* k1  = (float*)w;         w += (size_t)NB * NH * 4;
  float* k2  = (float*)w;         w += (size_t)NB * NH * 4;
  float* k3  = (float*)w;         w += (size_t)NB * NH * 4;           // 6 MB
  bf16* h    = (bf16*)w;          w += (size_t)NB * NOH * 2;          // 4 MB
  float* part = (float*)w;        w += (size_t)SPLITK * NB * NH * 4;  // 8 MB
  bf16* pred = (bf16*)w;          w += (size_t)NT * NB * NH * 2;      // 40 MB

  float* logits = (float*)d_out;  // [NT*NB, NC] fp32, softmaxed in place

  // Weight transpose-casts (chunk-swizzled) + state init (stateless)
  transpose_cast<<<dim3(NOH / 32, NH / 32), dim3(32, 8), 0, stream>>>(W1, W1bT, NH, NOH);
  transpose_cast<<<dim3(NH / 32, NOH / 32), dim3(32, 8), 0, stream>>>(W2, W2bT, NOH, NH);
  transpose_cast<<<dim3(NC / 32, NH / 32), dim3(32, 8), 0, stream>>>(Wf, WfT, NH, NC);
  init_state<<<(NB * NH) / 256, 256, 0, stream>>>(z, y, yb, pred);

  for (int t = 0; t < NT - 1; ++t) {
    for (int s = 1; s <= 4; ++s) {
      // GEMM1: h = tanh(yb @ W1 + b1)  [512x4096], 512 WGs, XCD-partitioned
      gemm_stage<0><<<512, 256, 0, stream>>>(yb, W1bT, b1, h, nullptr);
      // GEMM2: part[kz] = (h @ W2) K-chunks  [4 x 512x1024], 512 WGs
      gemm_stage<1><<<512, 256, 0, stream>>>(h, W2bT, nullptr, nullptr, part);
      // combine + RK4 stage algebra
      combine_stage<<<512, 256, 0, stream>>>(
          part, b2, y, yb, k1, k2, k3, pred + (size_t)(t + 1) * NB * NH, ts, t, s);
    }
  }

  // logits = pred @ Wf + bf   [20480 x 512], then softmax
  proj_gemm<<<dim3(NC / 128, (NT * NB) / 128), 256, 0, stream>>>(
      pred, WfT, NT * NB, NC, NH, bfv, logits);
  softmax_rows<<<(NT * NB) / 4, 256, 0, stream>>>(logits);
}